// Round 1
// baseline (1470.393 us; speedup 1.0000x reference)
//
#include <hip/hip_runtime.h>
#include <math.h>

#define Nn 200000
#define NT 3125   // Nn / 64

// ---- fold global y into lift bias: b2[j] = lift_b[j] + sum_d y[d]*lift_w[j][19+d]
__global__ void bias_fold_k(const float* __restrict__ y, const float* __restrict__ lw,
                            const float* __restrict__ lb, float* __restrict__ b2) {
    int j = threadIdx.x;
    float s = lb[j];
#pragma unroll
    for (int d = 0; d < 3; d++) s += y[d] * lw[j * 22 + 19 + d];
    b2[j] = s;
}

// ---- lift: h[n][j] = b2[j] + sum_f x[n][f]*W[j][f] + sum_d pos[n][d]*W[j][16+d]
__global__ void lift_k(const float* __restrict__ x, const float* __restrict__ pos,
                       const float* __restrict__ lw, const float* __restrict__ b2,
                       float* __restrict__ h) {
    int t = blockIdx.x * 256 + threadIdx.x;
    int n = t >> 7, j = t & 127;
    const float* wr = lw + j * 22;
    const float* xr = x + n * 16;
    const float* pr = pos + n * 3;
    float s = b2[j];
#pragma unroll
    for (int f = 0; f < 16; f++) s += xr[f] * wr[f];
#pragma unroll
    for (int d = 0; d < 3; d++) s += pr[d] * wr[16 + d];
    h[n * 128 + j] = s;
}

// ---- G = phi^T phi  (20x20), block-partial + atomicAdd
__global__ void gram_k(const float* __restrict__ phi, float* __restrict__ G) {
    __shared__ float ph[64 * 20];
    int t = threadIdx.x;
    int i0 = t / 20, j0 = t % 20;
    int p1 = t + 256;
    int i1 = p1 / 20, j1 = p1 % 20;
    float a0 = 0.f, a1 = 0.f;
    for (int tile = blockIdx.x; tile < NT; tile += gridDim.x) {
        const float* src = phi + tile * 1280;
        for (int idx = t; idx < 1280; idx += 256) ph[idx] = src[idx];
        __syncthreads();
        for (int n = 0; n < 64; n++) {
            const float* r = ph + n * 20;
            a0 += r[i0] * r[j0];
            if (p1 < 400) a1 += r[i1] * r[j1];
        }
        __syncthreads();
    }
    atomicAdd(&G[t], a0);
    if (p1 < 400) atomicAdd(&G[p1], a1);
}

// ---- Gauss-Jordan inverse of 20x20 (near-identity, no pivoting needed). 1 block x 64.
__global__ void ginv_k(const float* __restrict__ G, float* __restrict__ Gi) {
    __shared__ float A[20][40];
    __shared__ float colp[20];
    __shared__ float piv;
    int t = threadIdx.x;
    for (int idx = t; idx < 400; idx += 64) {
        int r = idx / 20, c = idx % 20;
        A[r][c] = G[idx];
        A[r][c + 20] = (r == c) ? 1.f : 0.f;
    }
    __syncthreads();
    for (int p = 0; p < 20; p++) {
        if (t == 0) piv = 1.f / A[p][p];
        __syncthreads();
        for (int c = t; c < 40; c += 64) A[p][c] *= piv;
        __syncthreads();
        if (t < 20) colp[t] = A[t][p];
        __syncthreads();
        for (int e = t; e < 800; e += 64) {
            int r = e / 40, c = e % 40;
            if (r != p) A[r][c] -= colp[r] * A[p][c];
        }
        __syncthreads();
    }
    for (int idx = t; idx < 400; idx += 64) {
        int r = idx / 20, c = idx % 20;
        Gi[idx] = A[r][c + 20];
    }
}

// ---- PT[k][j] = sum_n phi[n][k] * h[n][j]   (20x128), block-partial + atomicAdd
__global__ void ptv_k(const float* __restrict__ phi, const float* __restrict__ h,
                      float* __restrict__ PT) {
    __shared__ float ph[64 * 20];
    int t = threadIdx.x;
    int j = t & 127, kg = t >> 7;
    float acc[10];
#pragma unroll
    for (int i = 0; i < 10; i++) acc[i] = 0.f;
    for (int tile = blockIdx.x; tile < NT; tile += gridDim.x) {
        const float* src = phi + tile * 1280;
        for (int idx = t; idx < 1280; idx += 256) ph[idx] = src[idx];
        __syncthreads();
        const float* hb = h + tile * 64 * 128 + j;
        for (int n = 0; n < 64; n++) {
            float hv = hb[n * 128];
            const float* pr = ph + n * 20 + kg * 10;
#pragma unroll
            for (int i = 0; i < 10; i++) acc[i] += pr[i] * hv;
        }
        __syncthreads();
    }
#pragma unroll
    for (int i = 0; i < 10; i++) atomicAdd(&PT[(kg * 10 + i) * 128 + j], acc[i]);
}

// ---- v = Ginv @ PT (20x128); RV[k][i] = sum_j kernel[l][k][i][j] * v[k][j]. 1 block x 256.
__global__ void rv_k(const float* __restrict__ Gi, const float* __restrict__ PT,
                     const float* __restrict__ kern_l, float* __restrict__ RV) {
    __shared__ __align__(16) float v[2560];
    int t = threadIdx.x;
    for (int e = t; e < 2560; e += 256) {
        int k = e >> 7, jj = e & 127;
        const float* gr = Gi + k * 20;
        float s = 0.f;
#pragma unroll
        for (int m = 0; m < 20; m++) s += gr[m] * PT[m * 128 + jj];
        v[e] = s;
    }
    __syncthreads();
    for (int e = t; e < 2560; e += 256) {
        int k = e >> 7, i = e & 127;
        const float* kr = kern_l + (k * 128 + i) * 128;
        const float* vk = v + k * 128;
        float s = 0.f;
        for (int jj = 0; jj < 128; jj += 4) {
            float4 kv = *(const float4*)(kr + jj);
            float4 vv = *(const float4*)(vk + jj);
            s += kv.x * vv.x + kv.y * vv.y + kv.z * vv.z + kv.w * vv.w;
        }
        RV[e] = s;
    }
}

// ---- h[n][:] = elu( h @ W^T + phi @ RV ), in place, 64-node tiles.
__global__ __launch_bounds__(256) void update_k(float* __restrict__ h,
                                                const float* __restrict__ phi,
                                                const float* __restrict__ W,
                                                const float* __restrict__ RV) {
    union __align__(16) SM {
        struct { float Wt[64][132]; float ht[64][65]; } a;   // main loop
        struct { float RVs[20 * 128]; float phs[64 * 20]; } b; // epilogue
    };
    __shared__ SM sm;
    int t = threadIdx.x;
    int tx = t & 31, ty = t >> 5;
    int i0 = tx * 4;
    int n0 = blockIdx.x * 64;
    float acc[8][4];
#pragma unroll
    for (int m = 0; m < 8; m++)
#pragma unroll
        for (int c = 0; c < 4; c++) acc[m][c] = 0.f;

    for (int kc = 0; kc < 128; kc += 64) {
        __syncthreads();
        for (int idx = t; idx < 8192; idx += 256) {
            int jk = idx & 63, i = idx >> 6;
            sm.a.Wt[jk][i] = W[i * 128 + kc + jk];
        }
        for (int idx = t; idx < 4096; idx += 256) {
            int jk = idx & 63, n = idx >> 6;
            sm.a.ht[n][jk] = h[(n0 + n) * 128 + kc + jk];
        }
        __syncthreads();
#pragma unroll 4
        for (int jk = 0; jk < 64; jk++) {
            float4 w = *(const float4*)&sm.a.Wt[jk][i0];
#pragma unroll
            for (int m = 0; m < 8; m++) {
                float a = sm.a.ht[ty + 8 * m][jk];
                acc[m][0] += a * w.x; acc[m][1] += a * w.y;
                acc[m][2] += a * w.z; acc[m][3] += a * w.w;
            }
        }
    }
    __syncthreads();
    for (int idx = t; idx < 2560; idx += 256) sm.b.RVs[idx] = RV[idx];
    for (int idx = t; idx < 1280; idx += 256) sm.b.phs[idx] = phi[n0 * 20 + idx];
    __syncthreads();
#pragma unroll 4
    for (int k = 0; k < 20; k++) {
        float4 r = *(const float4*)&sm.b.RVs[k * 128 + i0];
#pragma unroll
        for (int m = 0; m < 8; m++) {
            float p = sm.b.phs[(ty + 8 * m) * 20 + k];
            acc[m][0] += p * r.x; acc[m][1] += p * r.y;
            acc[m][2] += p * r.z; acc[m][3] += p * r.w;
        }
    }
#pragma unroll
    for (int m = 0; m < 8; m++) {
        float4 o;
        o.x = acc[m][0] > 0.f ? acc[m][0] : __expf(acc[m][0]) - 1.f;
        o.y = acc[m][1] > 0.f ? acc[m][1] : __expf(acc[m][1]) - 1.f;
        o.z = acc[m][2] > 0.f ? acc[m][2] : __expf(acc[m][2]) - 1.f;
        o.w = acc[m][3] > 0.f ? acc[m][3] : __expf(acc[m][3]) - 1.f;
        *(float4*)&h[(n0 + ty + 8 * m) * 128 + i0] = o;
    }
}

// ---- out[n][o] = lower_b[o] + sum_j h[n][j] * lower_w[o][j]
__global__ void final_k(const float* __restrict__ h, const float* __restrict__ lw,
                        const float* __restrict__ lb, float* __restrict__ out) {
    __shared__ __align__(16) float hl[64][132];
    __shared__ __align__(16) float w[4][132];
    int t = threadIdx.x;
    int n0 = blockIdx.x * 64;
    for (int idx = t; idx < 512; idx += 256) w[idx >> 7][idx & 127] = lw[idx];
    for (int idx = t; idx < 8192; idx += 256) hl[idx >> 7][idx & 127] = h[n0 * 128 + idx];
    __syncthreads();
    int n = t >> 2, o = t & 3;
    float s = lb[o];
    for (int j = 0; j < 128; j += 4) {
        float4 hv = *(const float4*)&hl[n][j];
        float4 wv = *(const float4*)&w[o][j];
        s += hv.x * wv.x + hv.y * wv.y + hv.z * wv.z + hv.w * wv.w;
    }
    out[(n0 + n) * 4 + o] = s;
}

extern "C" void kernel_launch(void* const* d_in, const int* in_sizes, int n_in,
                              void* d_out, int out_size, void* d_ws, size_t ws_size,
                              hipStream_t stream) {
    (void)in_sizes; (void)n_in; (void)out_size; (void)ws_size;
    const float* x       = (const float*)d_in[0];
    const float* pos     = (const float*)d_in[1];
    const float* y       = (const float*)d_in[2];
    const float* phi     = (const float*)d_in[3];
    const float* lift_w  = (const float*)d_in[4];
    const float* lift_b  = (const float*)d_in[5];
    const float* lin_w   = (const float*)d_in[6];
    const float* kern    = (const float*)d_in[7];
    const float* lower_w = (const float*)d_in[8];
    const float* lower_b = (const float*)d_in[9];
    float* out = (float*)d_out;

    float* ws = (float*)d_ws;
    float* h  = ws;                       // Nn*128 floats = 102.4 MB
    float* b2 = ws + (size_t)Nn * 128;    // 128
    float* G  = b2 + 128;                 // 400
    float* Gi = G + 400;                  // 400
    float* PT = Gi + 400;                 // 2560
    float* RV = PT + 2560;                // 2560

    hipMemsetAsync(G, 0, 400 * sizeof(float), stream);
    bias_fold_k<<<1, 128, 0, stream>>>(y, lift_w, lift_b, b2);
    lift_k<<<(Nn * 128) / 256, 256, 0, stream>>>(x, pos, lift_w, b2, h);
    gram_k<<<256, 256, 0, stream>>>(phi, G);
    ginv_k<<<1, 64, 0, stream>>>(G, Gi);

    for (int l = 0; l < 4; l++) {
        hipMemsetAsync(PT, 0, 2560 * sizeof(float), stream);
        ptv_k<<<256, 256, 0, stream>>>(phi, h, PT);
        rv_k<<<1, 256, 0, stream>>>(Gi, PT, kern + (size_t)l * 20 * 128 * 128, RV);
        update_k<<<NT, 256, 0, stream>>>(h, phi, lin_w + (size_t)l * 128 * 128, RV);
    }
    final_k<<<NT, 256, 0, stream>>>(h, lower_w, lower_b, out);
}

// Round 2
// 1064.870 us; speedup vs baseline: 1.3808x; 1.3808x over previous
//
#include <hip/hip_runtime.h>
#include <math.h>

#define Nn 200000
#define NT 3125   // Nn / 64

// ---- fold global y into lift bias: b2[j] = lift_b[j] + sum_d y[d]*lift_w[j][19+d]
__global__ void bias_fold_k(const float* __restrict__ y, const float* __restrict__ lw,
                            const float* __restrict__ lb, float* __restrict__ b2) {
    int j = threadIdx.x;
    float s = lb[j];
#pragma unroll
    for (int d = 0; d < 3; d++) s += y[d] * lw[j * 22 + 19 + d];
    b2[j] = s;
}

// ---- lift as GEMM tile: h[n][j] = sum_{k<19} xs[n][k]*Wc[k][j] + Wc[19][j]
// xs = [x | pos | 1.0], Wc[k][j] = lift_w[j][k] (k<19), Wc[19][j] = b2[j]
__global__ __launch_bounds__(256) void lift_k(const float* __restrict__ x,
                                              const float* __restrict__ pos,
                                              const float* __restrict__ lw,
                                              const float* __restrict__ b2,
                                              float* __restrict__ h) {
    __shared__ float xs[64][21];
    __shared__ __align__(16) float Wc[20][132];
    int t = threadIdx.x;
    int n0 = blockIdx.x * 64;
    {   // x tile: 64 rows x 16 floats = 256 float4, one per thread
        int n = t >> 2, f4 = (t & 3) * 4;
        float4 xv = *(const float4*)(x + (size_t)(n0 + n) * 16 + f4);
        xs[n][f4 + 0] = xv.x; xs[n][f4 + 1] = xv.y;
        xs[n][f4 + 2] = xv.z; xs[n][f4 + 3] = xv.w;
    }
    if (t < 192) { int n = t / 3, d = t % 3; xs[n][16 + d] = pos[(size_t)(n0 + n) * 3 + d]; }
    if (t < 64) xs[t][19] = 1.f;
    for (int idx = t; idx < 2560; idx += 256) {
        int k = idx >> 7, j = idx & 127;
        Wc[k][j] = (k < 19) ? lw[j * 22 + k] : b2[j];
    }
    __syncthreads();
    int tx = t & 31, ty = t >> 5, i0 = tx * 4;
    float acc[8][4];
#pragma unroll
    for (int m = 0; m < 8; m++)
#pragma unroll
        for (int c = 0; c < 4; c++) acc[m][c] = 0.f;
#pragma unroll 4
    for (int k = 0; k < 20; k++) {
        float4 w = *(const float4*)&Wc[k][i0];
#pragma unroll
        for (int m = 0; m < 8; m++) {
            float a = xs[ty + 8 * m][k];
            acc[m][0] += a * w.x; acc[m][1] += a * w.y;
            acc[m][2] += a * w.z; acc[m][3] += a * w.w;
        }
    }
#pragma unroll
    for (int m = 0; m < 8; m++) {
        float4 o = { acc[m][0], acc[m][1], acc[m][2], acc[m][3] };
        *(float4*)&h[(size_t)(n0 + ty + 8 * m) * 128 + i0] = o;
    }
}

// ---- G = phi^T phi  (20x20), block-partial + atomicAdd
__global__ void gram_k(const float* __restrict__ phi, float* __restrict__ G) {
    __shared__ float ph[64 * 20];
    int t = threadIdx.x;
    int i0 = t / 20, j0 = t % 20;
    int p1 = t + 256;
    int i1 = p1 / 20, j1 = p1 % 20;
    float a0 = 0.f, a1 = 0.f;
    for (int tile = blockIdx.x; tile < NT; tile += gridDim.x) {
        const float* src = phi + tile * 1280;
        for (int idx = t; idx < 1280; idx += 256) ph[idx] = src[idx];
        __syncthreads();
        for (int n = 0; n < 64; n++) {
            const float* r = ph + n * 20;
            a0 += r[i0] * r[j0];
            if (p1 < 400) a1 += r[i1] * r[j1];
        }
        __syncthreads();
    }
    atomicAdd(&G[t], a0);
    if (p1 < 400) atomicAdd(&G[p1], a1);
}

// ---- Gauss-Jordan inverse of 20x20 (near-identity, no pivoting needed). 1 block x 64.
__global__ void ginv_k(const float* __restrict__ G, float* __restrict__ Gi) {
    __shared__ float A[20][40];
    __shared__ float colp[20];
    __shared__ float piv;
    int t = threadIdx.x;
    for (int idx = t; idx < 400; idx += 64) {
        int r = idx / 20, c = idx % 20;
        A[r][c] = G[idx];
        A[r][c + 20] = (r == c) ? 1.f : 0.f;
    }
    __syncthreads();
    for (int p = 0; p < 20; p++) {
        if (t == 0) piv = 1.f / A[p][p];
        __syncthreads();
        for (int c = t; c < 40; c += 64) A[p][c] *= piv;
        __syncthreads();
        if (t < 20) colp[t] = A[t][p];
        __syncthreads();
        for (int e = t; e < 800; e += 64) {
            int r = e / 40, c = e % 40;
            if (r != p) A[r][c] -= colp[r] * A[p][c];
        }
        __syncthreads();
    }
    for (int idx = t; idx < 400; idx += 64) {
        int r = idx / 20, c = idx % 20;
        Gi[idx] = A[r][c + 20];
    }
}

// ---- PT[k][j] = sum_n phi[n][k] * h[n][j]   (20x128), block-partial + atomicAdd
__global__ void ptv_k(const float* __restrict__ phi, const float* __restrict__ h,
                      float* __restrict__ PT) {
    __shared__ float ph[64 * 20];
    int t = threadIdx.x;
    int j = t & 127, kg = t >> 7;
    float acc[10];
#pragma unroll
    for (int i = 0; i < 10; i++) acc[i] = 0.f;
    for (int tile = blockIdx.x; tile < NT; tile += gridDim.x) {
        const float* src = phi + tile * 1280;
        for (int idx = t; idx < 1280; idx += 256) ph[idx] = src[idx];
        __syncthreads();
        const float* hb = h + (size_t)tile * 64 * 128 + j;
        for (int n = 0; n < 64; n++) {
            float hv = hb[n * 128];
            const float* pr = ph + n * 20 + kg * 10;
#pragma unroll
            for (int i = 0; i < 10; i++) acc[i] += pr[i] * hv;
        }
        __syncthreads();
    }
#pragma unroll
    for (int i = 0; i < 10; i++) atomicAdd(&PT[(kg * 10 + i) * 128 + j], acc[i]);
}

// ---- v[k][:] = Gi[k] @ PT; RV[k][i] = dot(kernel[l][k][i][:], v[k][:]).
// grid = 20 (one block per mode k), block = 128.
__global__ void rv_k(const float* __restrict__ Gi, const float* __restrict__ PT,
                     const float* __restrict__ kern_l, float* __restrict__ RV) {
    __shared__ __align__(16) float v[128];
    int k = blockIdx.x;
    int t = threadIdx.x;
    const float* gr = Gi + k * 20;
    float s = 0.f;
#pragma unroll
    for (int m = 0; m < 20; m++) s += gr[m] * PT[m * 128 + t];
    v[t] = s;
    __syncthreads();
    const float* kr = kern_l + (size_t)(k * 128 + t) * 128;
    float acc = 0.f;
#pragma unroll 8
    for (int jj = 0; jj < 128; jj += 4) {
        float4 kv = *(const float4*)(kr + jj);
        float4 vv = *(const float4*)(v + jj);
        acc += kv.x * vv.x + kv.y * vv.y + kv.z * vv.z + kv.w * vv.w;
    }
    RV[k * 128 + t] = acc;
}

// ---- h[n][:] = elu( h @ W^T + phi @ RV ), in place, 64-node tiles.
__global__ __launch_bounds__(256) void update_k(float* __restrict__ h,
                                                const float* __restrict__ phi,
                                                const float* __restrict__ W,
                                                const float* __restrict__ RV) {
    union __align__(16) SM {
        struct { float Wt[64][132]; float ht[64][65]; } a;   // main loop
        struct { float RVs[20 * 128]; float phs[64 * 20]; } b; // epilogue
    };
    __shared__ SM sm;
    int t = threadIdx.x;
    int tx = t & 31, ty = t >> 5;
    int i0 = tx * 4;
    int n0 = blockIdx.x * 64;
    float acc[8][4];
#pragma unroll
    for (int m = 0; m < 8; m++)
#pragma unroll
        for (int c = 0; c < 4; c++) acc[m][c] = 0.f;

    for (int kc = 0; kc < 128; kc += 64) {
        __syncthreads();
        for (int idx = t; idx < 8192; idx += 256) {
            int jk = idx & 63, i = idx >> 6;
            sm.a.Wt[jk][i] = W[i * 128 + kc + jk];
        }
        for (int idx = t; idx < 4096; idx += 256) {
            int jk = idx & 63, n = idx >> 6;
            sm.a.ht[n][jk] = h[(size_t)(n0 + n) * 128 + kc + jk];
        }
        __syncthreads();
#pragma unroll 4
        for (int jk = 0; jk < 64; jk++) {
            float4 w = *(const float4*)&sm.a.Wt[jk][i0];
#pragma unroll
            for (int m = 0; m < 8; m++) {
                float a = sm.a.ht[ty + 8 * m][jk];
                acc[m][0] += a * w.x; acc[m][1] += a * w.y;
                acc[m][2] += a * w.z; acc[m][3] += a * w.w;
            }
        }
    }
    __syncthreads();
    for (int idx = t; idx < 2560; idx += 256) sm.b.RVs[idx] = RV[idx];
    for (int idx = t; idx < 1280; idx += 256) sm.b.phs[idx] = phi[(size_t)n0 * 20 + idx];
    __syncthreads();
#pragma unroll 4
    for (int k = 0; k < 20; k++) {
        float4 r = *(const float4*)&sm.b.RVs[k * 128 + i0];
#pragma unroll
        for (int m = 0; m < 8; m++) {
            float p = sm.b.phs[(ty + 8 * m) * 20 + k];
            acc[m][0] += p * r.x; acc[m][1] += p * r.y;
            acc[m][2] += p * r.z; acc[m][3] += p * r.w;
        }
    }
#pragma unroll
    for (int m = 0; m < 8; m++) {
        float4 o;
        o.x = acc[m][0] > 0.f ? acc[m][0] : __expf(acc[m][0]) - 1.f;
        o.y = acc[m][1] > 0.f ? acc[m][1] : __expf(acc[m][1]) - 1.f;
        o.z = acc[m][2] > 0.f ? acc[m][2] : __expf(acc[m][2]) - 1.f;
        o.w = acc[m][3] > 0.f ? acc[m][3] : __expf(acc[m][3]) - 1.f;
        *(float4*)&h[(size_t)(n0 + ty + 8 * m) * 128 + i0] = o;
    }
}

// ---- out[n][o] = lower_b[o] + sum_j h[n][j] * lower_w[o][j]
__global__ void final_k(const float* __restrict__ h, const float* __restrict__ lw,
                        const float* __restrict__ lb, float* __restrict__ out) {
    __shared__ __align__(16) float hl[64][132];
    __shared__ __align__(16) float w[4][132];
    int t = threadIdx.x;
    int n0 = blockIdx.x * 64;
    for (int idx = t; idx < 512; idx += 256) w[idx >> 7][idx & 127] = lw[idx];
    for (int idx = t; idx < 8192; idx += 256) hl[idx >> 7][idx & 127] = h[(size_t)n0 * 128 + idx];
    __syncthreads();
    int n = t >> 2, o = t & 3;
    float s = lb[o];
    for (int j = 0; j < 128; j += 4) {
        float4 hv = *(const float4*)&hl[n][j];
        float4 wv = *(const float4*)&w[o][j];
        s += hv.x * wv.x + hv.y * wv.y + hv.z * wv.z + hv.w * wv.w;
    }
    out[(size_t)(n0 + n) * 4 + o] = s;
}

extern "C" void kernel_launch(void* const* d_in, const int* in_sizes, int n_in,
                              void* d_out, int out_size, void* d_ws, size_t ws_size,
                              hipStream_t stream) {
    (void)in_sizes; (void)n_in; (void)out_size; (void)ws_size;
    const float* x       = (const float*)d_in[0];
    const float* pos     = (const float*)d_in[1];
    const float* y       = (const float*)d_in[2];
    const float* phi     = (const float*)d_in[3];
    const float* lift_w  = (const float*)d_in[4];
    const float* lift_b  = (const float*)d_in[5];
    const float* lin_w   = (const float*)d_in[6];
    const float* kern    = (const float*)d_in[7];
    const float* lower_w = (const float*)d_in[8];
    const float* lower_b = (const float*)d_in[9];
    float* out = (float*)d_out;

    float* ws = (float*)d_ws;
    float* h  = ws;                       // Nn*128 floats = 102.4 MB
    float* b2 = ws + (size_t)Nn * 128;    // 128
    float* G  = b2 + 128;                 // 400
    float* Gi = G + 400;                  // 400
    float* PT = Gi + 400;                 // 2560
    float* RV = PT + 2560;                // 2560

    hipMemsetAsync(G, 0, 400 * sizeof(float), stream);
    bias_fold_k<<<1, 128, 0, stream>>>(y, lift_w, lift_b, b2);
    lift_k<<<NT, 256, 0, stream>>>(x, pos, lift_w, b2, h);
    gram_k<<<256, 256, 0, stream>>>(phi, G);
    ginv_k<<<1, 64, 0, stream>>>(G, Gi);

    for (int l = 0; l < 4; l++) {
        hipMemsetAsync(PT, 0, 2560 * sizeof(float), stream);
        ptv_k<<<512, 256, 0, stream>>>(phi, h, PT);
        rv_k<<<20, 128, 0, stream>>>(Gi, PT, kern + (size_t)l * 20 * 128 * 128, RV);
        update_k<<<NT, 256, 0, stream>>>(h, phi, lin_w + (size_t)l * 128 * 128, RV);
    }
    final_k<<<NT, 256, 0, stream>>>(h, lower_w, lower_b, out);
}

// Round 3
// 825.496 us; speedup vs baseline: 1.7812x; 1.2900x over previous
//
#include <hip/hip_runtime.h>
#include <math.h>

#define Nn 200000
#define NT 3125   // Nn / 64

typedef __attribute__((ext_vector_type(8))) short short8;
typedef __attribute__((ext_vector_type(16))) float floatx16;

// ---- bf16 split helpers (RNE) ----
__device__ __forceinline__ unsigned rnbf(float x) {
    unsigned u = __builtin_bit_cast(unsigned, x);
    return (u + 0x7fffu + ((u >> 16) & 1u)) >> 16;
}
__device__ __forceinline__ float asf(unsigned u) { return __builtin_bit_cast(float, u); }
// packed h element: low16 = hi bf16, high16 = lo bf16
__device__ __forceinline__ unsigned packf(float x) {
    unsigned hb = rnbf(x);
    float fh = asf(hb << 16);
    unsigned lb = rnbf(x - fh);
    return hb | (lb << 16);
}
__device__ __forceinline__ float unpackf(unsigned p) {
    return asf(p << 16) + asf(p & 0xffff0000u);
}

// ---- fold global y into lift bias
__global__ void bias_fold_k(const float* __restrict__ y, const float* __restrict__ lw,
                            const float* __restrict__ lb, float* __restrict__ b2) {
    int j = threadIdx.x;
    float s = lb[j];
#pragma unroll
    for (int d = 0; d < 3; d++) s += y[d] * lw[j * 22 + 19 + d];
    b2[j] = s;
}

// ---- split lin_w (4 layers, 65536 elems) into bf16 hi/lo
__global__ void wsplit_k(const float* __restrict__ lw, unsigned short* __restrict__ Wh,
                         unsigned short* __restrict__ Wl) {
    int i = blockIdx.x * 256 + threadIdx.x;
    float w = lw[i];
    unsigned hb = rnbf(w);
    float fh = asf(hb << 16);
    unsigned lb = rnbf(w - fh);
    Wh[i] = (unsigned short)hb;
    Wl[i] = (unsigned short)lb;
}

// ---- lift as GEMM tile, writes packed h
__global__ __launch_bounds__(256) void lift_k(const float* __restrict__ x,
                                              const float* __restrict__ pos,
                                              const float* __restrict__ lw,
                                              const float* __restrict__ b2,
                                              unsigned* __restrict__ hpk) {
    __shared__ float xs[64][21];
    __shared__ __align__(16) float Wc[20][132];
    int t = threadIdx.x;
    int n0 = blockIdx.x * 64;
    {
        int n = t >> 2, f4 = (t & 3) * 4;
        float4 xv = *(const float4*)(x + (size_t)(n0 + n) * 16 + f4);
        xs[n][f4 + 0] = xv.x; xs[n][f4 + 1] = xv.y;
        xs[n][f4 + 2] = xv.z; xs[n][f4 + 3] = xv.w;
    }
    if (t < 192) { int n = t / 3, d = t % 3; xs[n][16 + d] = pos[(size_t)(n0 + n) * 3 + d]; }
    if (t < 64) xs[t][19] = 1.f;
    for (int idx = t; idx < 2560; idx += 256) {
        int k = idx >> 7, j = idx & 127;
        Wc[k][j] = (k < 19) ? lw[j * 22 + k] : b2[j];
    }
    __syncthreads();
    int tx = t & 31, ty = t >> 5, i0 = tx * 4;
    float acc[8][4];
#pragma unroll
    for (int m = 0; m < 8; m++)
#pragma unroll
        for (int c = 0; c < 4; c++) acc[m][c] = 0.f;
#pragma unroll 4
    for (int k = 0; k < 20; k++) {
        float4 w = *(const float4*)&Wc[k][i0];
#pragma unroll
        for (int m = 0; m < 8; m++) {
            float a = xs[ty + 8 * m][k];
            acc[m][0] += a * w.x; acc[m][1] += a * w.y;
            acc[m][2] += a * w.z; acc[m][3] += a * w.w;
        }
    }
#pragma unroll
    for (int m = 0; m < 8; m++) {
        uint4 o;
        o.x = packf(acc[m][0]); o.y = packf(acc[m][1]);
        o.z = packf(acc[m][2]); o.w = packf(acc[m][3]);
        *(uint4*)&hpk[(size_t)(n0 + ty + 8 * m) * 128 + i0] = o;
    }
}

// ---- G = phi^T phi  (20x20)
__global__ void gram_k(const float* __restrict__ phi, float* __restrict__ G) {
    __shared__ float ph[64 * 20];
    int t = threadIdx.x;
    int i0 = t / 20, j0 = t % 20;
    int p1 = t + 256;
    int i1 = p1 / 20, j1 = p1 % 20;
    float a0 = 0.f, a1 = 0.f;
    for (int tile = blockIdx.x; tile < NT; tile += gridDim.x) {
        const float* src = phi + tile * 1280;
        for (int idx = t; idx < 1280; idx += 256) ph[idx] = src[idx];
        __syncthreads();
        for (int n = 0; n < 64; n++) {
            const float* r = ph + n * 20;
            a0 += r[i0] * r[j0];
            if (p1 < 400) a1 += r[i1] * r[j1];
        }
        __syncthreads();
    }
    atomicAdd(&G[t], a0);
    if (p1 < 400) atomicAdd(&G[p1], a1);
}

// ---- Gauss-Jordan inverse of 20x20
__global__ void ginv_k(const float* __restrict__ G, float* __restrict__ Gi) {
    __shared__ float A[20][40];
    __shared__ float colp[20];
    __shared__ float piv;
    int t = threadIdx.x;
    for (int idx = t; idx < 400; idx += 64) {
        int r = idx / 20, c = idx % 20;
        A[r][c] = G[idx];
        A[r][c + 20] = (r == c) ? 1.f : 0.f;
    }
    __syncthreads();
    for (int p = 0; p < 20; p++) {
        if (t == 0) piv = 1.f / A[p][p];
        __syncthreads();
        for (int c = t; c < 40; c += 64) A[p][c] *= piv;
        __syncthreads();
        if (t < 20) colp[t] = A[t][p];
        __syncthreads();
        for (int e = t; e < 800; e += 64) {
            int r = e / 40, c = e % 40;
            if (r != p) A[r][c] -= colp[r] * A[p][c];
        }
        __syncthreads();
    }
    for (int idx = t; idx < 400; idx += 64) {
        int r = idx / 20, c = idx % 20;
        Gi[idx] = A[r][c + 20];
    }
}

// ---- PT[k][j] = sum_n phi[n][k] * h[n][j]  (packed h)
__global__ void ptv_k(const float* __restrict__ phi, const unsigned* __restrict__ hpk,
                      float* __restrict__ PT) {
    __shared__ float ph[64 * 20];
    int t = threadIdx.x;
    int j = t & 127, kg = t >> 7;
    float acc[10];
#pragma unroll
    for (int i = 0; i < 10; i++) acc[i] = 0.f;
    for (int tile = blockIdx.x; tile < NT; tile += gridDim.x) {
        const float* src = phi + tile * 1280;
        for (int idx = t; idx < 1280; idx += 256) ph[idx] = src[idx];
        __syncthreads();
        const unsigned* hb = hpk + (size_t)tile * 64 * 128 + j;
        for (int n = 0; n < 64; n++) {
            float hv = unpackf(hb[n * 128]);
            const float* pr = ph + n * 20 + kg * 10;
#pragma unroll
            for (int i = 0; i < 10; i++) acc[i] += pr[i] * hv;
        }
        __syncthreads();
    }
#pragma unroll
    for (int i = 0; i < 10; i++) atomicAdd(&PT[(kg * 10 + i) * 128 + j], acc[i]);
}

// ---- v[k] = Gi[k] @ PT; RVT_hi/lo[i][k] = bf16-split of dot(kernel[l][k][i][:], v[k])
// grid = 20, block = 256 (two threads per output row).
__global__ void rv_k(const float* __restrict__ Gi, const float* __restrict__ PT,
                     const float* __restrict__ kern_l,
                     unsigned short* __restrict__ RVh, unsigned short* __restrict__ RVl) {
    __shared__ __align__(16) float v[128];
    __shared__ float part[128];
    int k = blockIdx.x;
    int t = threadIdx.x;
    if (t < 128) {
        const float* gr = Gi + k * 20;
        float s = 0.f;
#pragma unroll
        for (int m = 0; m < 20; m++) s += gr[m] * PT[m * 128 + t];
        v[t] = s;
    }
    __syncthreads();
    int i = t & 127, half = t >> 7;
    const float* kr = kern_l + (size_t)(k * 128 + i) * 128 + half * 64;
    const float* vk = v + half * 64;
    float acc = 0.f;
#pragma unroll 4
    for (int jj = 0; jj < 64; jj += 4) {
        float4 kv = *(const float4*)(kr + jj);
        float4 vv = *(const float4*)(vk + jj);
        acc += kv.x * vv.x + kv.y * vv.y + kv.z * vv.z + kv.w * vv.w;
    }
    if (half) part[i] = acc;
    __syncthreads();
    if (!half) {
        float rv = acc + part[i];
        unsigned hb = rnbf(rv);
        float fh = asf(hb << 16);
        unsigned lb = rnbf(rv - fh);
        RVh[i * 32 + k] = (unsigned short)hb;
        RVl[i * 32 + k] = (unsigned short)lb;
    }
}

// ---- MFMA update: h = elu(h @ W^T + phi @ RV), bf16x3 emulation, packed h in place.
// Block: 64 rows x 128 cols, 4 waves (wave = 32 rows x 64 cols = 2 MFMA col-tiles).
__global__ __launch_bounds__(256) void update_k(unsigned* __restrict__ hpk,
                                                const float* __restrict__ phi,
                                                const unsigned short* __restrict__ Wh,
                                                const unsigned short* __restrict__ Wl,
                                                const unsigned short* __restrict__ RVh,
                                                const unsigned short* __restrict__ RVl) {
    __shared__ union {
        unsigned As[64][132];  // packed h tile, stride 132 (bank-spread, 16B aligned)
        unsigned Ph[64][36];   // packed phi tile (k padded to 32 with zeros)
    } sm;
    int t = threadIdx.x;
    int n0 = blockIdx.x * 64;
    // stage packed h tile (coalesced uint4)
    for (int idx = t; idx < 2048; idx += 256) {
        int row = idx >> 5, c4 = (idx & 31) << 2;
        uint4 v = *(const uint4*)(hpk + (size_t)(n0 + row) * 128 + c4);
        *(uint4*)&sm.As[row][c4] = v;
    }
    __syncthreads();
    int lane = t & 63, w = t >> 6;
    int ln = lane & 31, hw = lane >> 5;
    int r0 = (w >> 1) * 32, ct0 = (w & 1) * 64;

    floatx16 acc0, acc1;
#pragma unroll
    for (int i = 0; i < 16; i++) { acc0[i] = 0.f; acc1[i] = 0.f; }

    const unsigned short* whp0 = Wh + (size_t)(ct0 + ln) * 128 + 8 * hw;
    const unsigned short* wlp0 = Wl + (size_t)(ct0 + ln) * 128 + 8 * hw;
    const unsigned short* whp1 = whp0 + 32 * 128;
    const unsigned short* wlp1 = wlp0 + 32 * 128;

#pragma unroll
    for (int ks = 0; ks < 8; ks++) {
        int k0 = ks * 16;
        const unsigned* ap = &sm.As[r0 + ln][k0 + 8 * hw];
        uint4 q0 = *(const uint4*)ap;
        uint4 q1 = *(const uint4*)(ap + 4);
        uint4 ah, al;
        ah.x = __builtin_amdgcn_perm(q0.y, q0.x, 0x05040100u);
        ah.y = __builtin_amdgcn_perm(q0.w, q0.z, 0x05040100u);
        ah.z = __builtin_amdgcn_perm(q1.y, q1.x, 0x05040100u);
        ah.w = __builtin_amdgcn_perm(q1.w, q1.z, 0x05040100u);
        al.x = __builtin_amdgcn_perm(q0.y, q0.x, 0x07060302u);
        al.y = __builtin_amdgcn_perm(q0.w, q0.z, 0x07060302u);
        al.z = __builtin_amdgcn_perm(q1.y, q1.x, 0x07060302u);
        al.w = __builtin_amdgcn_perm(q1.w, q1.z, 0x07060302u);
        short8 a_hi = __builtin_bit_cast(short8, ah);
        short8 a_lo = __builtin_bit_cast(short8, al);

        short8 b0h = __builtin_bit_cast(short8, *(const uint4*)(whp0 + k0));
        short8 b0l = __builtin_bit_cast(short8, *(const uint4*)(wlp0 + k0));
        short8 b1h = __builtin_bit_cast(short8, *(const uint4*)(whp1 + k0));
        short8 b1l = __builtin_bit_cast(short8, *(const uint4*)(wlp1 + k0));

        acc0 = __builtin_amdgcn_mfma_f32_32x32x16_bf16(a_hi, b0h, acc0, 0, 0, 0);
        acc0 = __builtin_amdgcn_mfma_f32_32x32x16_bf16(a_lo, b0h, acc0, 0, 0, 0);
        acc0 = __builtin_amdgcn_mfma_f32_32x32x16_bf16(a_hi, b0l, acc0, 0, 0, 0);
        acc1 = __builtin_amdgcn_mfma_f32_32x32x16_bf16(a_hi, b1h, acc1, 0, 0, 0);
        acc1 = __builtin_amdgcn_mfma_f32_32x32x16_bf16(a_lo, b1h, acc1, 0, 0, 0);
        acc1 = __builtin_amdgcn_mfma_f32_32x32x16_bf16(a_hi, b1l, acc1, 0, 0, 0);
    }

    // phi @ RV as 2 more k-steps (phi packed into LDS, RVT pre-split/transposed)
    __syncthreads();
    for (int idx = t; idx < 2048; idx += 256) {
        int row = idx >> 5, k = idx & 31;
        float pv = (k < 20) ? phi[(size_t)(n0 + row) * 20 + k] : 0.f;
        sm.Ph[row][k] = packf(pv);
    }
    __syncthreads();
#pragma unroll
    for (int ks = 0; ks < 2; ks++) {
        int k0 = ks * 16;
        const unsigned* ap = &sm.Ph[r0 + ln][k0 + 8 * hw];
        uint4 q0 = *(const uint4*)ap;
        uint4 q1 = *(const uint4*)(ap + 4);
        uint4 ah, al;
        ah.x = __builtin_amdgcn_perm(q0.y, q0.x, 0x05040100u);
        ah.y = __builtin_amdgcn_perm(q0.w, q0.z, 0x05040100u);
        ah.z = __builtin_amdgcn_perm(q1.y, q1.x, 0x05040100u);
        ah.w = __builtin_amdgcn_perm(q1.w, q1.z, 0x05040100u);
        al.x = __builtin_amdgcn_perm(q0.y, q0.x, 0x07060302u);
        al.y = __builtin_amdgcn_perm(q0.w, q0.z, 0x07060302u);
        al.z = __builtin_amdgcn_perm(q1.y, q1.x, 0x07060302u);
        al.w = __builtin_amdgcn_perm(q1.w, q1.z, 0x07060302u);
        short8 a_hi = __builtin_bit_cast(short8, ah);
        short8 a_lo = __builtin_bit_cast(short8, al);

        short8 b0h = __builtin_bit_cast(short8, *(const uint4*)(RVh + (size_t)(ct0 + ln) * 32 + k0 + 8 * hw));
        short8 b0l = __builtin_bit_cast(short8, *(const uint4*)(RVl + (size_t)(ct0 + ln) * 32 + k0 + 8 * hw));
        short8 b1h = __builtin_bit_cast(short8, *(const uint4*)(RVh + (size_t)(ct0 + 32 + ln) * 32 + k0 + 8 * hw));
        short8 b1l = __builtin_bit_cast(short8, *(const uint4*)(RVl + (size_t)(ct0 + 32 + ln) * 32 + k0 + 8 * hw));

        acc0 = __builtin_amdgcn_mfma_f32_32x32x16_bf16(a_hi, b0h, acc0, 0, 0, 0);
        acc0 = __builtin_amdgcn_mfma_f32_32x32x16_bf16(a_lo, b0h, acc0, 0, 0, 0);
        acc0 = __builtin_amdgcn_mfma_f32_32x32x16_bf16(a_hi, b0l, acc0, 0, 0, 0);
        acc1 = __builtin_amdgcn_mfma_f32_32x32x16_bf16(a_hi, b1h, acc1, 0, 0, 0);
        acc1 = __builtin_amdgcn_mfma_f32_32x32x16_bf16(a_lo, b1h, acc1, 0, 0, 0);
        acc1 = __builtin_amdgcn_mfma_f32_32x32x16_bf16(a_hi, b1l, acc1, 0, 0, 0);
    }

    // epilogue: elu + bf16-split pack + store (C/D: col=lane&31, row=(reg&3)+8*(reg>>2)+4*(lane>>5))
#pragma unroll
    for (int r = 0; r < 16; r++) {
        int row = (r & 3) + 8 * (r >> 2) + 4 * hw;
        size_t base = (size_t)(n0 + r0 + row) * 128;
        float v0 = acc0[r];
        v0 = v0 > 0.f ? v0 : __expf(v0) - 1.f;
        hpk[base + ct0 + ln] = packf(v0);
        float v1 = acc1[r];
        v1 = v1 > 0.f ? v1 : __expf(v1) - 1.f;
        hpk[base + ct0 + 32 + ln] = packf(v1);
    }
}

// ---- out[n][o] = lower_b[o] + sum_j h[n][j] * lower_w[o][j]  (packed h)
__global__ void final_k(const unsigned* __restrict__ hpk, const float* __restrict__ lw,
                        const float* __restrict__ lb, float* __restrict__ out) {
    __shared__ __align__(16) float hl[64][132];
    __shared__ __align__(16) float w[4][132];
    int t = threadIdx.x;
    int n0 = blockIdx.x * 64;
    for (int idx = t; idx < 512; idx += 256) w[idx >> 7][idx & 127] = lw[idx];
    for (int idx = t; idx < 8192; idx += 256)
        hl[idx >> 7][idx & 127] = unpackf(hpk[(size_t)n0 * 128 + idx]);
    __syncthreads();
    int n = t >> 2, o = t & 3;
    float s = lb[o];
    for (int j = 0; j < 128; j += 4) {
        float4 hv = *(const float4*)&hl[n][j];
        float4 wv = *(const float4*)&w[o][j];
        s += hv.x * wv.x + hv.y * wv.y + hv.z * wv.z + hv.w * wv.w;
    }
    out[(size_t)(n0 + n) * 4 + o] = s;
}

extern "C" void kernel_launch(void* const* d_in, const int* in_sizes, int n_in,
                              void* d_out, int out_size, void* d_ws, size_t ws_size,
                              hipStream_t stream) {
    (void)in_sizes; (void)n_in; (void)out_size; (void)ws_size;
    const float* x       = (const float*)d_in[0];
    const float* pos     = (const float*)d_in[1];
    const float* y       = (const float*)d_in[2];
    const float* phi     = (const float*)d_in[3];
    const float* lift_w  = (const float*)d_in[4];
    const float* lift_b  = (const float*)d_in[5];
    const float* lin_w   = (const float*)d_in[6];
    const float* kern    = (const float*)d_in[7];
    const float* lower_w = (const float*)d_in[8];
    const float* lower_b = (const float*)d_in[9];
    float* out = (float*)d_out;

    char* ws = (char*)d_ws;
    unsigned* hpk = (unsigned*)ws;                       // 102,400,000 B
    size_t off = (size_t)Nn * 128 * 4;
    float* b2 = (float*)(ws + off);        off += 512;
    float* G  = (float*)(ws + off);        off += 1600;
    float* Gi = (float*)(ws + off);        off += 1600;
    float* PT = (float*)(ws + off);        off += 10240;
    off = (off + 15) & ~(size_t)15;
    unsigned short* W_hi = (unsigned short*)(ws + off);  off += 131072;
    unsigned short* W_lo = (unsigned short*)(ws + off);  off += 131072;
    unsigned short* RVh  = (unsigned short*)(ws + off);  off += 8192;
    unsigned short* RVl  = (unsigned short*)(ws + off);  off += 8192;

    hipMemsetAsync(G, 0, 1600, stream);
    hipMemsetAsync(RVh, 0, 8192, stream);
    hipMemsetAsync(RVl, 0, 8192, stream);
    bias_fold_k<<<1, 128, 0, stream>>>(y, lift_w, lift_b, b2);
    wsplit_k<<<256, 256, 0, stream>>>(lin_w, W_hi, W_lo);
    lift_k<<<NT, 256, 0, stream>>>(x, pos, lift_w, b2, hpk);
    gram_k<<<256, 256, 0, stream>>>(phi, G);
    ginv_k<<<1, 64, 0, stream>>>(G, Gi);

    for (int l = 0; l < 4; l++) {
        hipMemsetAsync(PT, 0, 10240, stream);
        ptv_k<<<512, 256, 0, stream>>>(phi, hpk, PT);
        rv_k<<<20, 256, 0, stream>>>(Gi, PT, kern + (size_t)l * 20 * 128 * 128, RVh, RVl);
        update_k<<<NT, 256, 0, stream>>>(hpk, phi, W_hi + (size_t)l * 16384,
                                         W_lo + (size_t)l * 16384, RVh, RVl);
    }
    final_k<<<NT, 256, 0, stream>>>(hpk, lower_w, lower_b, out);
}